// Round 9
// baseline (269.281 us; speedup 1.0000x reference)
//
#include <hip/hip_runtime.h>
#include <hip/hip_fp16.h>

// ---------------------------------------------------------------------------
// LinearAggActor R28 (4-lane proj/fieldsoft: fix wave starvation):
//  - math (verified R2-R16): z0 = t2@(w3@w1)+b3@w1 (16-dim); z_k = A^k z0;
//    logits = cvec + sum_k relu(relu(z_k+b1)@w2+b2) @ M_k ; softmax.
//  - R27 post-mortem: proj_k = TOP dispatch 53-58us @ VALUBusy 6%, HBM 2%:
//    196 blocks = 784 waves on 1024 SIMDs (<1 wave/SIMD) — pure wave
//    starvation (compute is ~1.2us). fieldsoft same 196-block shape.
//  - R28: proj + fieldsoft split 4 LANES PER NODE (782 blocks, 3128 waves,
//    ~3/SIMD): t1-stage g-sum split per lane + __shfl_xor(.,1/2,4) allreduce;
//    t2/z/field redundant per lane (VALU idle anyway); stores via
//    compile-time selects (no runtime reg indexing -> no scratch), coalesced
//    uint2/float2. fieldsoft softmax cross-lane: 2 expf/lane (was 8).
//    __launch_bounds__(256,2) = 128 VGPR cap (64 spilled in R17; 256 starves).
//  - hop_k reverted to (256,4) (R25's verified best; R27a (256,6) not better).
//  - kept: cnts [bin][blk] (R27b), fp16 z rows + uint2 gathers (R25),
//    tier-sorted csrp_s/nd_s 2-epoch chain (R24).
//  - build (R10-15): binfill multisplit + setup on idle CUs; sentinel row n.
// ---------------------------------------------------------------------------

#define NB2MAX 400   // bins of 128 dsts: supports n <= 51200
#define NBLK   256   // binfill blocks
#define CAP2   32    // LDS staging per bin
#define CAPC   48    // per-(bin,block) cell capacity (mean 16, +8 sigma)
#define CAPB   6144  // per-bin dense CSR region (overflow tails only)
#define OVCAP  1024  // per-bin overflow region (statistically unused)
#define LCAP   6144  // csr2 per-bin LDS capacity (mean 4096, +32 sigma)
#define CAPN   64    // padded slots per node (mean 32, +5.7 sigma)

// blocks [0,NBLK): multisplit into private (bin,block) cells; packed
// (dloc<<16|src); LDS cursors; no global atomics on the hot path.
// blocks [NBLK, NBLK+9): setup role (R10-verified).
__global__ __launch_bounds__(1024) void binfill_k(
    const int* __restrict__ src, const int* __restrict__ dst, int E, int n,
    int* __restrict__ gcur, int* __restrict__ ovbuf,
    int* __restrict__ bins, int* __restrict__ cnts,
    const float* __restrict__ w1, const float* __restrict__ w3,
    const float* __restrict__ b3, const float* __restrict__ fc1w,
    const float* __restrict__ fc1b, const float* __restrict__ fc2w,
    const float* __restrict__ fc2b,
    float* __restrict__ M, float* __restrict__ cvec,
    float* __restrict__ W31, float* __restrict__ c31) {
    __shared__ int lbuf[NB2MAX * CAP2];
    __shared__ int lcnt[NB2MAX];
    __shared__ int lflush[NB2MAX];
    int tid = threadIdx.x;
    int NB = (n + 127) >> 7;

    if ((int)blockIdx.x >= NBLK) {
        // ---------------- setup role ----------------
        float* fl = (float*)lbuf;   // LDS reuse
        int s = (int)blockIdx.x - NBLK;
        if (s == 0) {
            if (tid < 256) {
                int i = tid >> 4, j = tid & 15;
                float a = 0.f;
                for (int g = 0; g < 64; g++) a += w3[i * 64 + g] * w1[g * 16 + j];
                W31[tid] = a;
            } else if (tid < 272) {
                int j = tid - 256;
                float a = 0.f;
                for (int g = 0; g < 64; g++) a += b3[g] * w1[g * 16 + j];
                c31[j] = a;
            } else if (tid >= 320 && tid < 384) {
                int h = tid - 320;
                float a = 0.f;
                for (int r = 0; r < 512; r++) a += b3[r & 63] * fc1w[r * 64 + h];
                fl[h] = a;   // u[h]
            }
            __syncthreads();
            if (tid < 8) {
                float a = fc2b[tid];
                for (int h = 0; h < 64; h++) a += (fc1b[h] + fl[h]) * fc2w[h * 8 + tid];
                cvec[tid] = a;
            }
        } else {
            int k = s - 1;
            {   // Q_k: one elem per thread
                int i = tid >> 6, h = tid & 63;
                float a = 0.f;
                const float* f1 = fc1w + (size_t)(k * 64) * 64 + h;
                for (int g = 0; g < 64; g++) a += w3[i * 64 + g] * f1[g * 64];
                fl[i * 64 + h] = a;
            }
            __syncthreads();
            if (tid < 128) {
                int i = tid >> 3, j = tid & 7;
                float a = 0.f;
                for (int h = 0; h < 64; h++) a += fl[i * 64 + h] * fc2w[h * 8 + j];
                M[k * 128 + i * 8 + j] = a;
            }
        }
        return;
    }

    // ---------------- binfill role ----------------
    for (int b = tid; b < NB; b += 1024) { lcnt[b] = 0; lflush[b] = 0; }
    __syncthreads();
    int blk = blockIdx.x;
    int chunk = (E + NBLK - 1) / NBLK;
    int beg = blk * chunk;
    int end = beg + chunk; if (end > E) end = E;
    for (int t0 = beg; t0 < end; t0 += 1024) {
        int e = t0 + tid;
        if (e < end) {
            int d = dst[e], s = src[e];
            if ((unsigned)d < (unsigned)n && (unsigned)s < (unsigned)n) {
                int b = d >> 7;
                int pk = ((d & 127) << 16) | s;
                int pos = atomicAdd(&lcnt[b], 1);
                if (pos < CAP2) lbuf[b * CAP2 + pos] = pk;
                else {  // statistically never
                    int p = atomicAdd(&gcur[b], 1);
                    if (p < OVCAP) ovbuf[b * OVCAP + p] = pk;
                }
            }
        }
        __syncthreads();
        for (int b = tid; b < NB; b += 1024) {
            int cnt = lcnt[b]; if (cnt > CAP2) cnt = CAP2;
            int fl2 = lflush[b];
            size_t cell = ((size_t)b * NBLK + blk) * CAPC;
            int base = 0;
            while (cnt - base >= 16) {
                if (fl2 + 16 <= CAPC) {
                    int* dp = bins + cell + fl2;
                    #pragma unroll
                    for (int q = 0; q < 16; q++) dp[q] = lbuf[b * CAP2 + base + q];
                    fl2 += 16;
                } else {  // cell overflow (statistically never)
                    int p = atomicAdd(&gcur[b], 16);
                    for (int q = 0; q < 16; q++)
                        if (p + q < OVCAP) ovbuf[b * OVCAP + p + q] = lbuf[b * CAP2 + base + q];
                }
                base += 16;
            }
            int rem = cnt - base;
            if (base > 0)
                for (int q = 0; q < rem; q++) lbuf[b * CAP2 + q] = lbuf[b * CAP2 + base + q];
            lcnt[b] = rem; lflush[b] = fl2;
        }
        __syncthreads();
    }
    for (int b = tid; b < NB; b += 1024) {
        int cnt = lcnt[b]; if (cnt > CAP2) cnt = CAP2;
        int fl2 = lflush[b];
        size_t cell = ((size_t)b * NBLK + blk) * CAPC;
        if (fl2 + cnt <= CAPC) {
            for (int q = 0; q < cnt; q++) bins[cell + fl2 + q] = lbuf[b * CAP2 + q];
            fl2 += cnt;
        } else {
            int p = atomicAdd(&gcur[b], cnt);
            for (int q = 0; q < cnt; q++)
                if (p + q < OVCAP) ovbuf[b * OVCAP + p + q] = lbuf[b * CAP2 + q];
        }
        cnts[(size_t)b * NBLK + blk] = fl2;   // [bin][blk] layout (R27b)
    }
}

// per-bin counting sort -> TIER-SORTED permuted padded ushort csrp_s +
// nd_s{node,deg} (+ dense tail csr/be for deg>64). One WG per bin; int-only.
// Tier regions: row = idx (t0), n+(idx-ns) (t1), 2n+(idx-ns-nm) (t2).
// csrp permutation: sorted slot j -> pos ((j&3)<<4)|(j>>2).
__global__ __launch_bounds__(256) void csr2_k(
    const int* __restrict__ bins, const int* __restrict__ cnts,
    const int* __restrict__ gcur, const int* __restrict__ ovbuf,
    unsigned short* __restrict__ csrp_s, int2* __restrict__ nd_s,
    int* __restrict__ csr, int2* __restrict__ be, int* __restrict__ lcnt3,
    int n) {
    __shared__ int hist[128], pref[128], cur[128], slot[128];
    __shared__ int scnt[NBLK];
    __shared__ int lbuf[LCAP];
    __shared__ int sov;
    __shared__ int ccnt[3], cbase[3];
    int tid = threadIdx.x;
    int b = blockIdx.x;
    if (tid < 128) { hist[tid] = 0; cur[tid] = 0; }
    if (tid < 3) ccnt[tid] = 0;
    scnt[tid] = cnts[(size_t)b * NBLK + tid];   // coalesced (R27b)
    if (tid == 0) {
        int g = gcur[b];
        sov = g < 0 ? 0 : (g > OVCAP ? OVCAP : g);
    }
    __syncthreads();
    {   // pass 1: histogram of dst-local
        int c = scnt[tid];
        size_t cell = ((size_t)b * NBLK + tid) * CAPC;
        for (int i = 0; i < c; i++) atomicAdd(&hist[bins[cell + i] >> 16], 1);
    }
    if (tid == 0)
        for (int i = 0; i < sov; i++) atomicAdd(&hist[ovbuf[b * OVCAP + i] >> 16], 1);
    __syncthreads();
    if (tid == 0) {
        int r = 0;
        for (int i = 0; i < 128; i++) { pref[i] = r; r += hist[i]; }
    }
    __syncthreads();
    {   // pass 2: place into LDS (bin-locally dense, sorted by dst)
        int c = scnt[tid];
        size_t cell = ((size_t)b * NBLK + tid) * CAPC;
        for (int i = 0; i < c; i++) {
            int pk = bins[cell + i];
            int dl = pk >> 16;
            int pos = pref[dl] + atomicAdd(&cur[dl], 1);
            if (pos < LCAP) lbuf[pos] = pk & 0xffff;
        }
    }
    if (tid == 0) {
        for (int i = 0; i < sov; i++) {
            int pk = ovbuf[b * OVCAP + i];
            int dl = pk >> 16;
            int pos = pref[dl] + atomicAdd(&cur[dl], 1);
            if (pos < LCAP) lbuf[pos] = pk & 0xffff;
        }
    }
    __syncthreads();
    // tier classification -> global sorted slot per node
    int myc = -1, lpos = 0;
    if (tid < 128) {
        int d = (b << 7) + tid;
        if (d < n) {
            int cnt = hist[tid];
            myc = cnt <= 32 ? 0 : (cnt <= 48 ? 1 : 2);
            lpos = atomicAdd(&ccnt[myc], 1);
        }
    }
    __syncthreads();
    if (tid < 3) cbase[tid] = atomicAdd(&lcnt3[tid], ccnt[tid]);
    __syncthreads();
    if (myc >= 0) {
        int d = (b << 7) + tid;
        int cnt = hist[tid];
        int s = myc * n + cbase[myc] + lpos;   // region base myc*n
        slot[tid] = s;
        nd_s[s] = make_int2(d, cnt);
        if (cnt > CAPN) {   // rare tail -> dense region + be (premult x4)
            int s0 = b * CAPB + pref[tid];
            be[d] = make_int2(s0 + CAPN, s0 + cnt);
            for (int j = CAPN; j < cnt; j++)
                csr[s0 + j] = lbuf[pref[tid] + j] << 2;
        }
    }
    __syncthreads();
    // permuted padded ushort CSR into sorted row; sentinel = n (zero row)
    for (int q = tid; q < 128 * CAPN; q += 256) {
        int dl = q >> 6, j = q & 63;
        int d = (b << 7) + dl;
        if (d >= n) break;
        int cnt = hist[dl];
        int v = (j < cnt) ? lbuf[pref[dl] + j] : n;
        int pos = ((j & 3) << 4) | (j >> 2);
        csrp_s[(size_t)slot[dl] * CAPN + pos] = (unsigned short)v;
    }
}

// unpack one uint2 (4 halfs = one channel quad) and accumulate
__device__ __forceinline__ void acc_row(uint2 u, float& ax, float& ay,
                                        float& az, float& aw) {
    __half2 p = *reinterpret_cast<const __half2*>(&u.x);
    __half2 q = *reinterpret_cast<const __half2*>(&u.y);
    float2 f = __half22float2(p), g = __half22float2(q);
    ax += f.x; ay += f.y; az += g.x; aw += g.y;
}

// proj: 4 LANES PER NODE (R28). t1 g-sum split per lane + shfl allreduce;
// t2/z/field0 redundant per lane; coalesced uint2/float2 stores via
// compile-time selects. (256,2) = 128 VGPR cap (no spill; 64 spilled in R17).
__global__ __launch_bounds__(256, 2) void proj_k(
    const float* __restrict__ x, __half* __restrict__ z0, __half* __restrict__ z1,
    float* __restrict__ logits,
    const float* __restrict__ w1, const float* __restrict__ b1,
    const float* __restrict__ w2, const float* __restrict__ b2,
    const float* __restrict__ W31, const float* __restrict__ c31,
    const float* __restrict__ M0, const float* __restrict__ cvec, int n) {
    __shared__ float sw1[1024], sw2[256], sW[256], sM[128];
    __shared__ float sb1[16], sb2[16], sc[16], scv[8];
    int tid = threadIdx.x;
    for (int i = tid; i < 1024; i += 256) sw1[i] = w1[i];
    sw2[tid] = w2[tid];
    sW[tid] = W31[tid];
    if (tid < 128) sM[tid] = M0[tid];
    if (tid < 16) { sb1[tid] = b1[tid]; sb2[tid] = b2[tid]; sc[tid] = c31[tid]; }
    if (tid < 8) scv[tid] = cvec[tid];
    __syncthreads();
    if (blockIdx.x == 0 && tid < 16) {   // zero sentinel row n of both bufs
        ((unsigned short*)z0)[(size_t)n * 16 + tid] = 0;
        ((unsigned short*)z1)[(size_t)n * 16 + tid] = 0;
    }
    int node = blockIdx.x * 64 + (tid >> 2);
    int sub = tid & 3;
    if (node >= n) return;
    // ---- t1 partials: this lane covers inputs g in [sub*16, sub*16+16) ----
    float t1[16];
    #pragma unroll
    for (int j = 0; j < 16; j++) t1[j] = 0.f;
    const float4* xp = (const float4*)(x + (size_t)node * 64 + sub * 16);
    #pragma unroll
    for (int q = 0; q < 4; q++) {
        float4 v = xp[q];
        const float* wr = sw1 + (sub * 16 + 4 * q) * 16;
        #pragma unroll
        for (int j = 0; j < 16; j++)
            t1[j] += v.x * wr[j] + v.y * wr[16 + j] + v.z * wr[32 + j] + v.w * wr[48 + j];
    }
    #pragma unroll
    for (int j = 0; j < 16; j++) {   // allreduce across the 4-lane group
        t1[j] += __shfl_xor(t1[j], 1, 4);
        t1[j] += __shfl_xor(t1[j], 2, 4);
        t1[j] = fmaxf(t1[j] + sb1[j], 0.f);
    }
    // ---- t2, z (redundant per lane; VALU is idle anyway) ----
    float t2[16];
    #pragma unroll
    for (int j = 0; j < 16; j++) {
        float a = sb2[j];
        #pragma unroll
        for (int i = 0; i < 16; i++) a += t1[i] * sw2[i * 16 + j];
        t2[j] = fmaxf(a, 0.f);
    }
    float z[16];
    #pragma unroll
    for (int j = 0; j < 16; j++) {
        float a = sc[j];
        #pragma unroll
        for (int i = 0; i < 16; i++) a += t2[i] * sW[i * 16 + j];
        z[j] = a;
    }
    // ---- z0 store: lane sub writes quarter (compile-time selects) ----
    {
        float s0 = sub == 0 ? z[0] : sub == 1 ? z[4] : sub == 2 ? z[8]  : z[12];
        float s1 = sub == 0 ? z[1] : sub == 1 ? z[5] : sub == 2 ? z[9]  : z[13];
        float s2 = sub == 0 ? z[2] : sub == 1 ? z[6] : sub == 2 ? z[10] : z[14];
        float s3 = sub == 0 ? z[3] : sub == 1 ? z[7] : sub == 2 ? z[11] : z[15];
        __half2 h01 = __floats2half2_rn(s0, s1);
        __half2 h23 = __floats2half2_rn(s2, s3);
        uint2 wz;
        wz.x = *reinterpret_cast<unsigned int*>(&h01);
        wz.y = *reinterpret_cast<unsigned int*>(&h23);
        ((uint2*)(z0 + (size_t)node * 16))[sub] = wz;
    }
    // ---- field0 (redundant per lane) ----
    float h[16], f2[16];
    #pragma unroll
    for (int i = 0; i < 16; i++) h[i] = fmaxf(z[i] + sb1[i], 0.f);
    #pragma unroll
    for (int j = 0; j < 16; j++) {
        float a = sb2[j];
        #pragma unroll
        for (int i = 0; i < 16; i++) a += h[i] * sw2[i * 16 + j];
        f2[j] = fmaxf(a, 0.f);
    }
    float l[8];
    #pragma unroll
    for (int j = 0; j < 8; j++) {
        float a = scv[j];
        #pragma unroll
        for (int i = 0; i < 16; i++) a += f2[i] * sM[i * 8 + j];
        l[j] = a;
    }
    float o0 = sub == 0 ? l[0] : sub == 1 ? l[2] : sub == 2 ? l[4] : l[6];
    float o1 = sub == 0 ? l[1] : sub == 1 ? l[3] : sub == 2 ? l[5] : l[7];
    ((float2*)(logits + (size_t)node * 8))[sub] = make_float2(o0, o1);
}

// One launch per hop. Blocks [0,FB): field(z_k) thread-per-node;
// blocks [FB,..): agg, 4 nodes/wave (16 lanes = 4 slot-groups x 4 chan-quads).
// z rows = 16 halfs = 32B; lane reads uint2; tier-sorted rows (2-epoch chain):
// tier0 8 gathers, tier1 12, tier2 16 + dense tail. (256,4) = R25 verified.
__global__ __launch_bounds__(256, 4) void hop_k(
    const __half* __restrict__ zin, __half* __restrict__ zout,
    float* __restrict__ logits,
    const unsigned short* __restrict__ csrp_s, const int2* __restrict__ nd_s,
    const int2* __restrict__ be, const int* __restrict__ csr,
    const int* __restrict__ lcnt3,
    const float* __restrict__ w2, const float* __restrict__ b1,
    const float* __restrict__ b2, const float* __restrict__ M, int n, int FB) {
    __shared__ float sw2[256], sM[128], sb1[16], sb2[16];
    int tid = threadIdx.x;
    if ((int)blockIdx.x < FB) {
        // ---- field role ----
        sw2[tid] = w2[tid];
        if (tid < 128) sM[tid] = M[tid];
        if (tid < 16) { sb1[tid] = b1[tid]; sb2[tid] = b2[tid]; }
        __syncthreads();
        int nid = blockIdx.x * 256 + tid;
        if (nid >= n) return;
        float h[16];
        const __half2* zp = (const __half2*)(zin + (size_t)nid * 16);
        #pragma unroll
        for (int q = 0; q < 8; q++) {
            float2 f = __half22float2(zp[q]);
            h[2 * q] = f.x; h[2 * q + 1] = f.y;
        }
        #pragma unroll
        for (int i = 0; i < 16; i++) h[i] = fmaxf(h[i] + sb1[i], 0.f);
        float t2[16];
        #pragma unroll
        for (int j = 0; j < 16; j++) {
            float a = sb2[j];
            #pragma unroll
            for (int i = 0; i < 16; i++) a += h[i] * sw2[i * 16 + j];
            t2[j] = fmaxf(a, 0.f);
        }
        float* lp = logits + (size_t)nid * 8;
        #pragma unroll
        for (int j = 0; j < 8; j++) {
            float l = 0.f;
            #pragma unroll
            for (int i = 0; i < 16; i++) l += t2[i] * sM[i * 8 + j];
            lp[j] += l;
        }
        return;
    }
    // ---- agg role: 4 nodes per wave, tier-sorted direct rows ----
    int wave = tid >> 6;
    int lane = tid & 63;
    int quarter = lane >> 4;              // which node of the 4
    int l16 = lane & 15;
    int t4 = l16 >> 2, ch = l16 & 3;      // slot-group 0..3, chan-quad 0..3
    int idx = (((int)blockIdx.x - FB) * 4 + wave) * 4 + quarter;
    if (idx >= n) return;
    int ns = lcnt3[0], nm = lcnt3[1];     // uniform scalar loads
    int tier; size_t row;
    if (idx < ns)           { tier = 0; row = (size_t)idx; }
    else if (idx < ns + nm) { tier = 1; row = (size_t)n + (idx - ns); }
    else                    { tier = 2; row = 2 * (size_t)n + (idx - ns - nm); }
    int2 nd = nd_s[row];                  // {node, deg} — same epoch as ip
    int node = nd.x, degi = nd.y;
    const uint4* ip = (const uint4*)(csrp_s + (row << 6));
    uint4 pa = ip[t4 * 2];                // sorted slots j = t4, t4+4, ..., t4+28
    int r0 = pa.x & 0xffff, r1 = pa.x >> 16;
    int r2 = pa.y & 0xffff, r3 = pa.y >> 16;
    int r4 = pa.z & 0xffff, r5 = pa.z >> 16;
    int r6 = pa.w & 0xffff, r7 = pa.w >> 16;
    const uint2* z2 = (const uint2*)zin;  // row stride = 4 uint2 (32B)
    uint2 u0 = z2[((size_t)r0 << 2) + ch];   // sentinel n -> zero row
    uint2 u1 = z2[((size_t)r1 << 2) + ch];
    uint2 u2 = z2[((size_t)r2 << 2) + ch];
    uint2 u3 = z2[((size_t)r3 << 2) + ch];
    uint2 u4 = z2[((size_t)r4 << 2) + ch];
    uint2 u5 = z2[((size_t)r5 << 2) + ch];
    uint2 u6 = z2[((size_t)r6 << 2) + ch];
    uint2 u7 = z2[((size_t)r7 << 2) + ch];
    float ax = 0.f, ay = 0.f, az = 0.f, aw = 0.f;
    acc_row(u0, ax, ay, az, aw); acc_row(u1, ax, ay, az, aw);
    acc_row(u2, ax, ay, az, aw); acc_row(u3, ax, ay, az, aw);
    acc_row(u4, ax, ay, az, aw); acc_row(u5, ax, ay, az, aw);
    acc_row(u6, ax, ay, az, aw); acc_row(u7, ax, ay, az, aw);
    if (tier >= 1) {
        uint4 pb = ip[t4 * 2 + 1];        // sorted slots j = t4+32..t4+60
        int r8 = pb.x & 0xffff, r9 = pb.x >> 16;
        int rA = pb.y & 0xffff, rB = pb.y >> 16;
        uint2 u8 = z2[((size_t)r8 << 2) + ch];
        uint2 u9 = z2[((size_t)r9 << 2) + ch];
        uint2 uA = z2[((size_t)rA << 2) + ch];
        uint2 uB = z2[((size_t)rB << 2) + ch];
        acc_row(u8, ax, ay, az, aw); acc_row(u9, ax, ay, az, aw);
        acc_row(uA, ax, ay, az, aw); acc_row(uB, ax, ay, az, aw);
        if (tier == 2) {
            int rC = pb.z & 0xffff, rD = pb.z >> 16;
            int rE = pb.w & 0xffff, rF = pb.w >> 16;
            uint2 uC = z2[((size_t)rC << 2) + ch];
            uint2 uD = z2[((size_t)rD << 2) + ch];
            uint2 uE = z2[((size_t)rE << 2) + ch];
            uint2 uF = z2[((size_t)rF << 2) + ch];
            acc_row(uC, ax, ay, az, aw); acc_row(uD, ax, ay, az, aw);
            acc_row(uE, ax, ay, az, aw); acc_row(uF, ax, ay, az, aw);
            if (degi > CAPN) {            // rare tail via dense csr (4 slots)
                int2 r = be[node];
                for (int q = r.x + t4; q < r.y; q += 4) {
                    uint2 u = z2[(size_t)csr[q] + ch];   // csr premult x4
                    acc_row(u, ax, ay, az, aw);
                }
            }
        }
    }
    // reduce over 4 slot-groups within this 16-lane quarter
    #pragma unroll
    for (int off = 8; off >= 4; off >>= 1) {
        ax += __shfl_down(ax, off, 16);
        ay += __shfl_down(ay, off, 16);
        az += __shfl_down(az, off, 16);
        aw += __shfl_down(aw, off, 16);
    }
    if (l16 < 4) {
        float inv = 1.f / (float)(degi > 0 ? degi : 1);
        __half2 h01 = __floats2half2_rn(ax * inv, ay * inv);
        __half2 h23 = __floats2half2_rn(az * inv, aw * inv);
        uint2 w;
        w.x = *reinterpret_cast<unsigned int*>(&h01);
        w.y = *reinterpret_cast<unsigned int*>(&h23);
        ((uint2*)(zout + (size_t)node * 16))[l16] = w;
    }
}

// final: logits += field(z7, M7); softmax. 4 LANES PER NODE (R28):
// f2/logits redundant per lane; cross-lane softmax (2 expf/lane, was 8);
// coalesced float2 RMW.
__global__ __launch_bounds__(256, 2) void fieldsoft_k(
    const __half* __restrict__ z, float* __restrict__ logits,
    const float* __restrict__ w2, const float* __restrict__ b1,
    const float* __restrict__ b2, const float* __restrict__ M, int n) {
    __shared__ float sw2[256], sM[128], sb1[16], sb2[16];
    int tid = threadIdx.x;
    sw2[tid] = w2[tid];
    if (tid < 128) sM[tid] = M[tid];
    if (tid < 16) { sb1[tid] = b1[tid]; sb2[tid] = b2[tid]; }
    __syncthreads();
    int node = blockIdx.x * 64 + (tid >> 2);
    int sub = tid & 3;
    if (node >= n) return;
    float h[16];
    const __half2* zp = (const __half2*)(z + (size_t)node * 16);
    #pragma unroll
    for (int q = 0; q < 8; q++) {
        float2 f = __half22float2(zp[q]);
        h[2 * q] = f.x; h[2 * q + 1] = f.y;
    }
    #pragma unroll
    for (int i = 0; i < 16; i++) h[i] = fmaxf(h[i] + sb1[i], 0.f);
    float t2[16];
    #pragma unroll
    for (int j = 0; j < 16; j++) {
        float a = sb2[j];
        #pragma unroll
        for (int i = 0; i < 16; i++) a += h[i] * sw2[i * 16 + j];
        t2[j] = fmaxf(a, 0.f);
    }
    float l[8];
    #pragma unroll
    for (int j = 0; j < 8; j++) {
        float a = 0.f;
        #pragma unroll
        for (int i = 0; i < 16; i++) a += t2[i] * sM[i * 8 + j];
        l[j] = a;
    }
    // this lane finishes logit pair (2*sub, 2*sub+1)
    float2 lp2 = ((float2*)(logits + (size_t)node * 8))[sub];
    float a0 = sub == 0 ? l[0] : sub == 1 ? l[2] : sub == 2 ? l[4] : l[6];
    float a1 = sub == 0 ? l[1] : sub == 1 ? l[3] : sub == 2 ? l[5] : l[7];
    float v0 = lp2.x + a0, v1 = lp2.y + a1;
    float m = fmaxf(v0, v1);
    m = fmaxf(m, __shfl_xor(m, 1, 4));
    m = fmaxf(m, __shfl_xor(m, 2, 4));
    float e0 = expf(v0 - m), e1 = expf(v1 - m);
    float s = e0 + e1;
    s += __shfl_xor(s, 1, 4);
    s += __shfl_xor(s, 2, 4);
    float inv = 1.f / s;
    ((float2*)(logits + (size_t)node * 8))[sub] = make_float2(e0 * inv, e1 * inv);
}

extern "C" void kernel_launch(void* const* d_in, const int* in_sizes, int n_in,
                              void* d_out, int out_size, void* d_ws, size_t ws_size,
                              hipStream_t stream) {
    const float* x    = (const float*)d_in[0];
    const int*   ei   = (const int*)d_in[1];
    const float* w1   = (const float*)d_in[2];
    const float* b1   = (const float*)d_in[3];
    const float* w2   = (const float*)d_in[4];
    const float* b2   = (const float*)d_in[5];
    const float* w3   = (const float*)d_in[6];
    const float* b3   = (const float*)d_in[7];
    const float* fc1w = (const float*)d_in[8];
    const float* fc1b = (const float*)d_in[9];
    const float* fc2w = (const float*)d_in[10];
    const float* fc2b = (const float*)d_in[11];
    float* out = (float*)d_out;

    int n = in_sizes[0] / 64;
    int E = in_sizes[1] / 2;
    int NB = (n + 127) >> 7;   // 391 for n=50000; NB <= NB2MAX
    const int* src = ei;
    const int* dst = ei + E;

    char* ws = (char*)d_ws;
    auto carve = [&](size_t bytes) {
        char* p = ws;
        ws += (bytes + 255) & ~((size_t)255);
        return p;
    };
    int*   gcur    = (int*)carve((size_t)NB * 4);
    int*   lcnt3   = (int*)carve(16);                 // contiguous after gcur pad
    int*   ovbuf   = (int*)carve((size_t)NB * OVCAP * 4);
    int*   binsbuf = (int*)carve((size_t)NB * NBLK * CAPC * 4);
    int*   cnts    = (int*)carve((size_t)NB * NBLK * 4);
    unsigned short* csrp_s = (unsigned short*)carve((size_t)3 * n * CAPN * 2); // tier-sorted
    int2*  nd_s    = (int2*)carve((size_t)3 * n * 8);                          // {node,deg}
    int*   csr     = (int*)carve((size_t)NB * CAPB * 4);
    int2*  be      = (int2*)carve((size_t)n * 8);
    __half* buf0   = (__half*)carve((size_t)(n + 1) * 16 * 2);  // +1 zero row
    __half* buf1   = (__half*)carve((size_t)(n + 1) * 16 * 2);
    float* M       = (float*)carve(1024 * 4);
    float* cvec    = (float*)carve(8 * 4);
    float* W31     = (float*)carve(256 * 4);
    float* c31     = (float*)carve(16 * 4);

    // one memset covers gcur (padded to 256) + lcnt3 (next carve slot)
    size_t gpad = ((size_t)NB * 4 + 255) & ~((size_t)255);
    hipMemsetAsync(gcur, 0, gpad + 16, stream);
    binfill_k<<<NBLK + 9, 1024, 0, stream>>>(src, dst, E, n, gcur, ovbuf, binsbuf, cnts,
                                             w1, w3, b3, fc1w, fc1b, fc2w, fc2b,
                                             M, cvec, W31, c31);
    csr2_k<<<NB, 256, 0, stream>>>(binsbuf, cnts, gcur, ovbuf,
                                   csrp_s, nd_s, csr, be, lcnt3, n);

    int FB  = (n + 255) / 256;    // field blocks (hop field role)
    int FB4 = (n + 63) / 64;      // 4-lane proj/fieldsoft blocks
    int AB  = (n + 15) / 16;      // agg blocks (4 nodes/wave, 4 waves/block)
    proj_k<<<FB4, 256, 0, stream>>>(x, buf0, buf1, out, w1, b1, w2, b2,
                                    W31, c31, M, cvec, n);

    __half* cur = buf0;
    __half* nxt = buf1;
    // hop 1: agg only (field0 applied in proj)
    hop_k<<<AB, 256, 0, stream>>>(cur, nxt, out, csrp_s, nd_s, be, csr, lcnt3,
                                  w2, b1, b2, M, n, 0);
    { __half* t = cur; cur = nxt; nxt = t; }
    // hops 2..7: field(z_k, M_k) + agg(z_k -> z_{k+1}) in one launch
    for (int k = 1; k <= 6; k++) {
        hop_k<<<FB + AB, 256, 0, stream>>>(cur, nxt, out, csrp_s, nd_s, be, csr,
                                           lcnt3, w2, b1, b2, M + k * 128, n, FB);
        __half* t = cur; cur = nxt; nxt = t;
    }
    // final: field(z7, M7) + softmax
    fieldsoft_k<<<FB4, 256, 0, stream>>>(cur, out, w2, b1, b2, M + 7 * 128, n);
}

// Round 10
// 243.178 us; speedup vs baseline: 1.1073x; 1.1073x over previous
//
#include <hip/hip_runtime.h>
#include <hip/hip_fp16.h>

// ---------------------------------------------------------------------------
// LinearAggActor R29 (R25 base + j-parallel low-latency proj):
//  - math (verified R2-R16): z0 = t2@(w3@w1)+b3@w1 (16-dim); z_k = A^k z0;
//    logits = cvec + sum_k relu(relu(z_k+b1)@w2+b2) @ M_k ; softmax.
//  - R27/R28 post-mortem: proj dur == ONE WAVE's serial time (53us @ occ 8%,
//    VGPR 256; 47us @ occ 15%, VGPR 128 + 2.4M LDS conflicts). Thread-per-
//    node keeps 64+ live regs and chains ~2600 LDS-broadcast FMAs at ~50
//    cyc/op (every lgkmcnt exposed). More waves barely helps; the chain must
//    shrink.
//  - R29 proj: J-PARALLEL, 16 lanes/node (tid = nl*16 + j). Lane owns one
//    output dim/stage: t1_j = 64-deep LDS FMA (conflict-free: sw1 16-consec
//    x 4-group broadcast; sx padded to 68 -> distinct banks per node-group);
//    t2/z/f2 via __shfl(.,i,16) (VALU-speed); logits via __shfl_xor reduce +
//    compile-time select writer (rule #20). ~30 live VGPR -> (256,4) 64 cap,
//    3125 blocks, 16 waves/CU. Per-wave chain ~1-2us.
//  - Everything else = R25 verified best (240.2us): fp16 z rows + uint2
//    gathers, tier-sorted csrp_s/nd_s 2-epoch chain, hop (256,4),
//    thread-per-node fieldsoft, original cnts layout.
//  - build (R10-15): binfill multisplit + setup on idle CUs; sentinel row n.
// ---------------------------------------------------------------------------

#define NB2MAX 400   // bins of 128 dsts: supports n <= 51200
#define NBLK   256   // binfill blocks
#define CAP2   32    // LDS staging per bin
#define CAPC   48    // per-(bin,block) cell capacity (mean 16, +8 sigma)
#define CAPB   6144  // per-bin dense CSR region (overflow tails only)
#define OVCAP  1024  // per-bin overflow region (statistically unused)
#define LCAP   6144  // csr2 per-bin LDS capacity (mean 4096, +32 sigma)
#define CAPN   64    // padded slots per node (mean 32, +5.7 sigma)

// blocks [0,NBLK): multisplit into private (bin,block) cells; packed
// (dloc<<16|src); LDS cursors; no global atomics on the hot path.
// blocks [NBLK, NBLK+9): setup role (R10-verified).
__global__ __launch_bounds__(1024) void binfill_k(
    const int* __restrict__ src, const int* __restrict__ dst, int E, int n,
    int* __restrict__ gcur, int* __restrict__ ovbuf,
    int* __restrict__ bins, int* __restrict__ cnts,
    const float* __restrict__ w1, const float* __restrict__ w3,
    const float* __restrict__ b3, const float* __restrict__ fc1w,
    const float* __restrict__ fc1b, const float* __restrict__ fc2w,
    const float* __restrict__ fc2b,
    float* __restrict__ M, float* __restrict__ cvec,
    float* __restrict__ W31, float* __restrict__ c31) {
    __shared__ int lbuf[NB2MAX * CAP2];
    __shared__ int lcnt[NB2MAX];
    __shared__ int lflush[NB2MAX];
    int tid = threadIdx.x;
    int NB = (n + 127) >> 7;

    if ((int)blockIdx.x >= NBLK) {
        // ---------------- setup role ----------------
        float* fl = (float*)lbuf;   // LDS reuse
        int s = (int)blockIdx.x - NBLK;
        if (s == 0) {
            if (tid < 256) {
                int i = tid >> 4, j = tid & 15;
                float a = 0.f;
                for (int g = 0; g < 64; g++) a += w3[i * 64 + g] * w1[g * 16 + j];
                W31[tid] = a;
            } else if (tid < 272) {
                int j = tid - 256;
                float a = 0.f;
                for (int g = 0; g < 64; g++) a += b3[g] * w1[g * 16 + j];
                c31[j] = a;
            } else if (tid >= 320 && tid < 384) {
                int h = tid - 320;
                float a = 0.f;
                for (int r = 0; r < 512; r++) a += b3[r & 63] * fc1w[r * 64 + h];
                fl[h] = a;   // u[h]
            }
            __syncthreads();
            if (tid < 8) {
                float a = fc2b[tid];
                for (int h = 0; h < 64; h++) a += (fc1b[h] + fl[h]) * fc2w[h * 8 + tid];
                cvec[tid] = a;
            }
        } else {
            int k = s - 1;
            {   // Q_k: one elem per thread
                int i = tid >> 6, h = tid & 63;
                float a = 0.f;
                const float* f1 = fc1w + (size_t)(k * 64) * 64 + h;
                for (int g = 0; g < 64; g++) a += w3[i * 64 + g] * f1[g * 64];
                fl[i * 64 + h] = a;
            }
            __syncthreads();
            if (tid < 128) {
                int i = tid >> 3, j = tid & 7;
                float a = 0.f;
                for (int h = 0; h < 64; h++) a += fl[i * 64 + h] * fc2w[h * 8 + j];
                M[k * 128 + i * 8 + j] = a;
            }
        }
        return;
    }

    // ---------------- binfill role ----------------
    for (int b = tid; b < NB; b += 1024) { lcnt[b] = 0; lflush[b] = 0; }
    __syncthreads();
    int blk = blockIdx.x;
    int chunk = (E + NBLK - 1) / NBLK;
    int beg = blk * chunk;
    int end = beg + chunk; if (end > E) end = E;
    for (int t0 = beg; t0 < end; t0 += 1024) {
        int e = t0 + tid;
        if (e < end) {
            int d = dst[e], s = src[e];
            if ((unsigned)d < (unsigned)n && (unsigned)s < (unsigned)n) {
                int b = d >> 7;
                int pk = ((d & 127) << 16) | s;
                int pos = atomicAdd(&lcnt[b], 1);
                if (pos < CAP2) lbuf[b * CAP2 + pos] = pk;
                else {  // statistically never
                    int p = atomicAdd(&gcur[b], 1);
                    if (p < OVCAP) ovbuf[b * OVCAP + p] = pk;
                }
            }
        }
        __syncthreads();
        for (int b = tid; b < NB; b += 1024) {
            int cnt = lcnt[b]; if (cnt > CAP2) cnt = CAP2;
            int fl2 = lflush[b];
            size_t cell = ((size_t)b * NBLK + blk) * CAPC;
            int base = 0;
            while (cnt - base >= 16) {
                if (fl2 + 16 <= CAPC) {
                    int* dp = bins + cell + fl2;
                    #pragma unroll
                    for (int q = 0; q < 16; q++) dp[q] = lbuf[b * CAP2 + base + q];
                    fl2 += 16;
                } else {  // cell overflow (statistically never)
                    int p = atomicAdd(&gcur[b], 16);
                    for (int q = 0; q < 16; q++)
                        if (p + q < OVCAP) ovbuf[b * OVCAP + p + q] = lbuf[b * CAP2 + base + q];
                }
                base += 16;
            }
            int rem = cnt - base;
            if (base > 0)
                for (int q = 0; q < rem; q++) lbuf[b * CAP2 + q] = lbuf[b * CAP2 + base + q];
            lcnt[b] = rem; lflush[b] = fl2;
        }
        __syncthreads();
    }
    for (int b = tid; b < NB; b += 1024) {
        int cnt = lcnt[b]; if (cnt > CAP2) cnt = CAP2;
        int fl2 = lflush[b];
        size_t cell = ((size_t)b * NBLK + blk) * CAPC;
        if (fl2 + cnt <= CAPC) {
            for (int q = 0; q < cnt; q++) bins[cell + fl2 + q] = lbuf[b * CAP2 + q];
            fl2 += cnt;
        } else {
            int p = atomicAdd(&gcur[b], cnt);
            for (int q = 0; q < cnt; q++)
                if (p + q < OVCAP) ovbuf[b * OVCAP + p + q] = lbuf[b * CAP2 + q];
        }
        cnts[(size_t)blk * NB + b] = fl2;
    }
}

// per-bin counting sort -> TIER-SORTED permuted padded ushort csrp_s +
// nd_s{node,deg} (+ dense tail csr/be for deg>64). One WG per bin; int-only.
// Tier regions: row = idx (t0), n+(idx-ns) (t1), 2n+(idx-ns-nm) (t2).
// csrp permutation: sorted slot j -> pos ((j&3)<<4)|(j>>2).
__global__ __launch_bounds__(256) void csr2_k(
    const int* __restrict__ bins, const int* __restrict__ cnts,
    const int* __restrict__ gcur, const int* __restrict__ ovbuf,
    unsigned short* __restrict__ csrp_s, int2* __restrict__ nd_s,
    int* __restrict__ csr, int2* __restrict__ be, int* __restrict__ lcnt3,
    int n) {
    __shared__ int hist[128], pref[128], cur[128], slot[128];
    __shared__ int scnt[NBLK];
    __shared__ int lbuf[LCAP];
    __shared__ int sov;
    __shared__ int ccnt[3], cbase[3];
    int tid = threadIdx.x;
    int NB = (n + 127) >> 7;
    int b = blockIdx.x;
    if (tid < 128) { hist[tid] = 0; cur[tid] = 0; }
    if (tid < 3) ccnt[tid] = 0;
    scnt[tid] = cnts[(size_t)tid * NB + b];
    if (tid == 0) {
        int g = gcur[b];
        sov = g < 0 ? 0 : (g > OVCAP ? OVCAP : g);
    }
    __syncthreads();
    {   // pass 1: histogram of dst-local
        int c = scnt[tid];
        size_t cell = ((size_t)b * NBLK + tid) * CAPC;
        for (int i = 0; i < c; i++) atomicAdd(&hist[bins[cell + i] >> 16], 1);
    }
    if (tid == 0)
        for (int i = 0; i < sov; i++) atomicAdd(&hist[ovbuf[b * OVCAP + i] >> 16], 1);
    __syncthreads();
    if (tid == 0) {
        int r = 0;
        for (int i = 0; i < 128; i++) { pref[i] = r; r += hist[i]; }
    }
    __syncthreads();
    {   // pass 2: place into LDS (bin-locally dense, sorted by dst)
        int c = scnt[tid];
        size_t cell = ((size_t)b * NBLK + tid) * CAPC;
        for (int i = 0; i < c; i++) {
            int pk = bins[cell + i];
            int dl = pk >> 16;
            int pos = pref[dl] + atomicAdd(&cur[dl], 1);
            if (pos < LCAP) lbuf[pos] = pk & 0xffff;
        }
    }
    if (tid == 0) {
        for (int i = 0; i < sov; i++) {
            int pk = ovbuf[b * OVCAP + i];
            int dl = pk >> 16;
            int pos = pref[dl] + atomicAdd(&cur[dl], 1);
            if (pos < LCAP) lbuf[pos] = pk & 0xffff;
        }
    }
    __syncthreads();
    // tier classification -> global sorted slot per node
    int myc = -1, lpos = 0;
    if (tid < 128) {
        int d = (b << 7) + tid;
        if (d < n) {
            int cnt = hist[tid];
            myc = cnt <= 32 ? 0 : (cnt <= 48 ? 1 : 2);
            lpos = atomicAdd(&ccnt[myc], 1);
        }
    }
    __syncthreads();
    if (tid < 3) cbase[tid] = atomicAdd(&lcnt3[tid], ccnt[tid]);
    __syncthreads();
    if (myc >= 0) {
        int d = (b << 7) + tid;
        int cnt = hist[tid];
        int s = myc * n + cbase[myc] + lpos;   // region base myc*n
        slot[tid] = s;
        nd_s[s] = make_int2(d, cnt);
        if (cnt > CAPN) {   // rare tail -> dense region + be (premult x4)
            int s0 = b * CAPB + pref[tid];
            be[d] = make_int2(s0 + CAPN, s0 + cnt);
            for (int j = CAPN; j < cnt; j++)
                csr[s0 + j] = lbuf[pref[tid] + j] << 2;
        }
    }
    __syncthreads();
    // permuted padded ushort CSR into sorted row; sentinel = n (zero row)
    for (int q = tid; q < 128 * CAPN; q += 256) {
        int dl = q >> 6, j = q & 63;
        int d = (b << 7) + dl;
        if (d >= n) break;
        int cnt = hist[dl];
        int v = (j < cnt) ? lbuf[pref[dl] + j] : n;
        int pos = ((j & 3) << 4) | (j >> 2);
        csrp_s[(size_t)slot[dl] * CAPN + pos] = (unsigned short)v;
    }
}

// unpack one uint2 (4 halfs = one channel quad) and accumulate
__device__ __forceinline__ void acc_row(uint2 u, float& ax, float& ay,
                                        float& az, float& aw) {
    __half2 p = *reinterpret_cast<const __half2*>(&u.x);
    __half2 q = *reinterpret_cast<const __half2*>(&u.y);
    float2 f = __half22float2(p), g = __half22float2(q);
    ax += f.x; ay += f.y; az += g.x; aw += g.y;
}

// proj R29: J-PARALLEL, 16 lanes per node (tid = nl*16 + j). Lane j owns
// output dim j of every stage; intermediates pass via __shfl(.,i,16).
// t1: 64-deep LDS FMA, conflict-free (sw1 16-consec x 4-group broadcast;
// sx rows padded to 68 floats -> 4 node-groups hit distinct banks).
// ~30 live VGPR -> (256,4) 64 cap, no spill; 16 nodes/block, 16 waves/CU.
__global__ __launch_bounds__(256, 4) void proj_k(
    const float* __restrict__ x, __half* __restrict__ z0, __half* __restrict__ z1,
    float* __restrict__ logits,
    const float* __restrict__ w1, const float* __restrict__ b1,
    const float* __restrict__ w2, const float* __restrict__ b2,
    const float* __restrict__ W31, const float* __restrict__ c31,
    const float* __restrict__ M0, const float* __restrict__ cvec, int n) {
    __shared__ float sx[16 * 68];        // 16 node rows, padded stride 68
    __shared__ float sw1[1024], sw2[256], sW[256], sM[128];
    __shared__ float sb1[16], sb2[16], sc[16], scv[8];
    int tid = threadIdx.x;
    for (int i = tid; i < 1024; i += 256) sw1[i] = w1[i];
    sw2[tid] = w2[tid];
    sW[tid] = W31[tid];
    if (tid < 128) sM[tid] = M0[tid];
    if (tid < 16) { sb1[tid] = b1[tid]; sb2[tid] = b2[tid]; sc[tid] = c31[tid]; }
    if (tid < 8) scv[tid] = cvec[tid];
    if (blockIdx.x == 0 && tid < 16) {   // zero sentinel row n of both bufs
        ((unsigned short*)z0)[(size_t)n * 16 + tid] = 0;
        ((unsigned short*)z1)[(size_t)n * 16 + tid] = 0;
    }
    // stage x: 16 rows x 64 floats, coalesced float4 (16 thr x 16B per row)
    int node0 = blockIdx.x * 16;
    {
        int r = tid >> 4, c4 = tid & 15;
        if (node0 + r < n) {
            float4 v = ((const float4*)(x + (size_t)(node0 + r) * 64))[c4];
            float* dstp = sx + r * 68 + c4 * 4;
            dstp[0] = v.x; dstp[1] = v.y; dstp[2] = v.z; dstp[3] = v.w;
        }
    }
    __syncthreads();
    int nl = tid >> 4, jj = tid & 15;
    int node = node0 + nl;
    if (node >= n) return;
    // ---- t1_j: 64-deep FMA over LDS (reads independent, prefetchable) ----
    float t1 = 0.f;
    const float* xr = sx + nl * 68;
    #pragma unroll
    for (int g = 0; g < 64; g++) t1 += xr[g] * sw1[g * 16 + jj];
    t1 = fmaxf(t1 + sb1[jj], 0.f);
    // ---- t2_j via shuffle-gather of t1_i ----
    float t2 = sb2[jj];
    #pragma unroll
    for (int i = 0; i < 16; i++) t2 += __shfl(t1, i, 16) * sw2[i * 16 + jj];
    t2 = fmaxf(t2, 0.f);
    // ---- z_j ----
    float zv = sc[jj];
    #pragma unroll
    for (int i = 0; i < 16; i++) zv += __shfl(t2, i, 16) * sW[i * 16 + jj];
    z0[(size_t)node * 16 + jj] = __float2half(zv);   // 2B/lane, 32B/node
    // ---- field0: h_j, f2_j, logits via xor-reduce over j ----
    float hv = fmaxf(zv + sb1[jj], 0.f);
    float f2 = sb2[jj];
    #pragma unroll
    for (int i = 0; i < 16; i++) f2 += __shfl(hv, i, 16) * sw2[i * 16 + jj];
    f2 = fmaxf(f2, 0.f);
    float p0 = f2 * sM[jj * 8 + 0], p1 = f2 * sM[jj * 8 + 1];
    float p2 = f2 * sM[jj * 8 + 2], p3 = f2 * sM[jj * 8 + 3];
    float p4 = f2 * sM[jj * 8 + 4], p5 = f2 * sM[jj * 8 + 5];
    float p6 = f2 * sM[jj * 8 + 6], p7 = f2 * sM[jj * 8 + 7];
    #pragma unroll
    for (int off = 1; off < 16; off <<= 1) {
        p0 += __shfl_xor(p0, off, 16); p1 += __shfl_xor(p1, off, 16);
        p2 += __shfl_xor(p2, off, 16); p3 += __shfl_xor(p3, off, 16);
        p4 += __shfl_xor(p4, off, 16); p5 += __shfl_xor(p5, off, 16);
        p6 += __shfl_xor(p6, off, 16); p7 += __shfl_xor(p7, off, 16);
    }
    if (jj < 8) {   // compile-time select chain (no runtime reg indexing)
        float myp = jj == 0 ? p0 : jj == 1 ? p1 : jj == 2 ? p2 : jj == 3 ? p3
                  : jj == 4 ? p4 : jj == 5 ? p5 : jj == 6 ? p6 : p7;
        logits[(size_t)node * 8 + jj] = scv[jj] + myp;
    }
}

// One launch per hop. Blocks [0,FB): field(z_k) thread-per-node;
// blocks [FB,..): agg, 4 nodes/wave (16 lanes = 4 slot-groups x 4 chan-quads).
// z rows = 16 halfs = 32B; lane reads uint2; tier-sorted rows (2-epoch chain):
// tier0 8 gathers, tier1 12, tier2 16 + dense tail. (256,4) = R25 verified.
__global__ __launch_bounds__(256, 4) void hop_k(
    const __half* __restrict__ zin, __half* __restrict__ zout,
    float* __restrict__ logits,
    const unsigned short* __restrict__ csrp_s, const int2* __restrict__ nd_s,
    const int2* __restrict__ be, const int* __restrict__ csr,
    const int* __restrict__ lcnt3,
    const float* __restrict__ w2, const float* __restrict__ b1,
    const float* __restrict__ b2, const float* __restrict__ M, int n, int FB) {
    __shared__ float sw2[256], sM[128], sb1[16], sb2[16];
    int tid = threadIdx.x;
    if ((int)blockIdx.x < FB) {
        // ---- field role ----
        sw2[tid] = w2[tid];
        if (tid < 128) sM[tid] = M[tid];
        if (tid < 16) { sb1[tid] = b1[tid]; sb2[tid] = b2[tid]; }
        __syncthreads();
        int nid = blockIdx.x * 256 + tid;
        if (nid >= n) return;
        float h[16];
        const __half2* zp = (const __half2*)(zin + (size_t)nid * 16);
        #pragma unroll
        for (int q = 0; q < 8; q++) {
            float2 f = __half22float2(zp[q]);
            h[2 * q] = f.x; h[2 * q + 1] = f.y;
        }
        #pragma unroll
        for (int i = 0; i < 16; i++) h[i] = fmaxf(h[i] + sb1[i], 0.f);
        float t2[16];
        #pragma unroll
        for (int j = 0; j < 16; j++) {
            float a = sb2[j];
            #pragma unroll
            for (int i = 0; i < 16; i++) a += h[i] * sw2[i * 16 + j];
            t2[j] = fmaxf(a, 0.f);
        }
        float* lp = logits + (size_t)nid * 8;
        #pragma unroll
        for (int j = 0; j < 8; j++) {
            float l = 0.f;
            #pragma unroll
            for (int i = 0; i < 16; i++) l += t2[i] * sM[i * 8 + j];
            lp[j] += l;
        }
        return;
    }
    // ---- agg role: 4 nodes per wave, tier-sorted direct rows ----
    int wave = tid >> 6;
    int lane = tid & 63;
    int quarter = lane >> 4;              // which node of the 4
    int l16 = lane & 15;
    int t4 = l16 >> 2, ch = l16 & 3;      // slot-group 0..3, chan-quad 0..3
    int idx = (((int)blockIdx.x - FB) * 4 + wave) * 4 + quarter;
    if (idx >= n) return;
    int ns = lcnt3[0], nm = lcnt3[1];     // uniform scalar loads
    int tier; size_t row;
    if (idx < ns)           { tier = 0; row = (size_t)idx; }
    else if (idx < ns + nm) { tier = 1; row = (size_t)n + (idx - ns); }
    else                    { tier = 2; row = 2 * (size_t)n + (idx - ns - nm); }
    int2 nd = nd_s[row];                  // {node, deg} — same epoch as ip
    int node = nd.x, degi = nd.y;
    const uint4* ip = (const uint4*)(csrp_s + (row << 6));
    uint4 pa = ip[t4 * 2];                // sorted slots j = t4, t4+4, ..., t4+28
    int r0 = pa.x & 0xffff, r1 = pa.x >> 16;
    int r2 = pa.y & 0xffff, r3 = pa.y >> 16;
    int r4 = pa.z & 0xffff, r5 = pa.z >> 16;
    int r6 = pa.w & 0xffff, r7 = pa.w >> 16;
    const uint2* z2 = (const uint2*)zin;  // row stride = 4 uint2 (32B)
    uint2 u0 = z2[((size_t)r0 << 2) + ch];   // sentinel n -> zero row
    uint2 u1 = z2[((size_t)r1 << 2) + ch];
    uint2 u2 = z2[((size_t)r2 << 2) + ch];
    uint2 u3 = z2[((size_t)r3 << 2) + ch];
    uint2 u4 = z2[((size_t)r4 << 2) + ch];
    uint2 u5 = z2[((size_t)r5 << 2) + ch];
    uint2 u6 = z2[((size_t)r6 << 2) + ch];
    uint2 u7 = z2[((size_t)r7 << 2) + ch];
    float ax = 0.f, ay = 0.f, az = 0.f, aw = 0.f;
    acc_row(u0, ax, ay, az, aw); acc_row(u1, ax, ay, az, aw);
    acc_row(u2, ax, ay, az, aw); acc_row(u3, ax, ay, az, aw);
    acc_row(u4, ax, ay, az, aw); acc_row(u5, ax, ay, az, aw);
    acc_row(u6, ax, ay, az, aw); acc_row(u7, ax, ay, az, aw);
    if (tier >= 1) {
        uint4 pb = ip[t4 * 2 + 1];        // sorted slots j = t4+32..t4+60
        int r8 = pb.x & 0xffff, r9 = pb.x >> 16;
        int rA = pb.y & 0xffff, rB = pb.y >> 16;
        uint2 u8 = z2[((size_t)r8 << 2) + ch];
        uint2 u9 = z2[((size_t)r9 << 2) + ch];
        uint2 uA = z2[((size_t)rA << 2) + ch];
        uint2 uB = z2[((size_t)rB << 2) + ch];
        acc_row(u8, ax, ay, az, aw); acc_row(u9, ax, ay, az, aw);
        acc_row(uA, ax, ay, az, aw); acc_row(uB, ax, ay, az, aw);
        if (tier == 2) {
            int rC = pb.z & 0xffff, rD = pb.z >> 16;
            int rE = pb.w & 0xffff, rF = pb.w >> 16;
            uint2 uC = z2[((size_t)rC << 2) + ch];
            uint2 uD = z2[((size_t)rD << 2) + ch];
            uint2 uE = z2[((size_t)rE << 2) + ch];
            uint2 uF = z2[((size_t)rF << 2) + ch];
            acc_row(uC, ax, ay, az, aw); acc_row(uD, ax, ay, az, aw);
            acc_row(uE, ax, ay, az, aw); acc_row(uF, ax, ay, az, aw);
            if (degi > CAPN) {            // rare tail via dense csr (4 slots)
                int2 r = be[node];
                for (int q = r.x + t4; q < r.y; q += 4) {
                    uint2 u = z2[(size_t)csr[q] + ch];   // csr premult x4
                    acc_row(u, ax, ay, az, aw);
                }
            }
        }
    }
    // reduce over 4 slot-groups within this 16-lane quarter
    #pragma unroll
    for (int off = 8; off >= 4; off >>= 1) {
        ax += __shfl_down(ax, off, 16);
        ay += __shfl_down(ay, off, 16);
        az += __shfl_down(az, off, 16);
        aw += __shfl_down(aw, off, 16);
    }
    if (l16 < 4) {
        float inv = 1.f / (float)(degi > 0 ? degi : 1);
        __half2 h01 = __floats2half2_rn(ax * inv, ay * inv);
        __half2 h23 = __floats2half2_rn(az * inv, aw * inv);
        uint2 w;
        w.x = *reinterpret_cast<unsigned int*>(&h01);
        w.y = *reinterpret_cast<unsigned int*>(&h23);
        ((uint2*)(zout + (size_t)node * 16))[l16] = w;
    }
}

// final: logits += field(z7, M7); softmax; thread-per-node (R25 verified)
__global__ __launch_bounds__(256) void fieldsoft_k(
    const __half* __restrict__ z, float* __restrict__ logits,
    const float* __restrict__ w2, const float* __restrict__ b1,
    const float* __restrict__ b2, const float* __restrict__ M, int n) {
    __shared__ float sw2[256], sM[128], sb1[16], sb2[16];
    int tid = threadIdx.x;
    sw2[tid] = w2[tid];
    if (tid < 128) sM[tid] = M[tid];
    if (tid < 16) { sb1[tid] = b1[tid]; sb2[tid] = b2[tid]; }
    __syncthreads();
    int nid = blockIdx.x * 256 + tid;
    if (nid >= n) return;
    float h[16];
    const __half2* zp = (const __half2*)(z + (size_t)nid * 16);
    #pragma unroll
    for (int q = 0; q < 8; q++) {
        float2 f = __half22float2(zp[q]);
        h[2 * q] = f.x; h[2 * q + 1] = f.y;
    }
    #pragma unroll
    for (int i = 0; i < 16; i++) h[i] = fmaxf(h[i] + sb1[i], 0.f);
    float t2[16];
    #pragma unroll
    for (int j = 0; j < 16; j++) {
        float a = sb2[j];
        #pragma unroll
        for (int i = 0; i < 16; i++) a += h[i] * sw2[i * 16 + j];
        t2[j] = fmaxf(a, 0.f);
    }
    float4* lp4 = (float4*)(logits + (size_t)nid * 8);
    float4 l0 = lp4[0], l1 = lp4[1];
    float v[8] = {l0.x, l0.y, l0.z, l0.w, l1.x, l1.y, l1.z, l1.w};
    #pragma unroll
    for (int j = 0; j < 8; j++) {
        float l = 0.f;
        #pragma unroll
        for (int i = 0; i < 16; i++) l += t2[i] * sM[i * 8 + j];
        v[j] += l;
    }
    float m = v[0];
    #pragma unroll
    for (int j = 1; j < 8; j++) m = fmaxf(m, v[j]);
    float s = 0.f;
    #pragma unroll
    for (int j = 0; j < 8; j++) { v[j] = expf(v[j] - m); s += v[j]; }
    float inv = 1.f / s;
    lp4[0] = make_float4(v[0] * inv, v[1] * inv, v[2] * inv, v[3] * inv);
    lp4[1] = make_float4(v[4] * inv, v[5] * inv, v[6] * inv, v[7] * inv);
}

extern "C" void kernel_launch(void* const* d_in, const int* in_sizes, int n_in,
                              void* d_out, int out_size, void* d_ws, size_t ws_size,
                              hipStream_t stream) {
    const float* x    = (const float*)d_in[0];
    const int*   ei   = (const int*)d_in[1];
    const float* w1   = (const float*)d_in[2];
    const float* b1   = (const float*)d_in[3];
    const float* w2   = (const float*)d_in[4];
    const float* b2   = (const float*)d_in[5];
    const float* w3   = (const float*)d_in[6];
    const float* b3   = (const float*)d_in[7];
    const float* fc1w = (const float*)d_in[8];
    const float* fc1b = (const float*)d_in[9];
    const float* fc2w = (const float*)d_in[10];
    const float* fc2b = (const float*)d_in[11];
    float* out = (float*)d_out;

    int n = in_sizes[0] / 64;
    int E = in_sizes[1] / 2;
    int NB = (n + 127) >> 7;   // 391 for n=50000; NB <= NB2MAX
    const int* src = ei;
    const int* dst = ei + E;

    char* ws = (char*)d_ws;
    auto carve = [&](size_t bytes) {
        char* p = ws;
        ws += (bytes + 255) & ~((size_t)255);
        return p;
    };
    int*   gcur    = (int*)carve((size_t)NB * 4);
    int*   lcnt3   = (int*)carve(16);                 // contiguous after gcur pad
    int*   ovbuf   = (int*)carve((size_t)NB * OVCAP * 4);
    int*   binsbuf = (int*)carve((size_t)NB * NBLK * CAPC * 4);
    int*   cnts    = (int*)carve((size_t)NBLK * NB * 4);
    unsigned short* csrp_s = (unsigned short*)carve((size_t)3 * n * CAPN * 2); // tier-sorted
    int2*  nd_s    = (int2*)carve((size_t)3 * n * 8);                          // {node,deg}
    int*   csr     = (int*)carve((size_t)NB * CAPB * 4);
    int2*  be      = (int2*)carve((size_t)n * 8);
    __half* buf0   = (__half*)carve((size_t)(n + 1) * 16 * 2);  // +1 zero row
    __half* buf1   = (__half*)carve((size_t)(n + 1) * 16 * 2);
    float* M       = (float*)carve(1024 * 4);
    float* cvec    = (float*)carve(8 * 4);
    float* W31     = (float*)carve(256 * 4);
    float* c31     = (float*)carve(16 * 4);

    // one memset covers gcur (padded to 256) + lcnt3 (next carve slot)
    size_t gpad = ((size_t)NB * 4 + 255) & ~((size_t)255);
    hipMemsetAsync(gcur, 0, gpad + 16, stream);
    binfill_k<<<NBLK + 9, 1024, 0, stream>>>(src, dst, E, n, gcur, ovbuf, binsbuf, cnts,
                                             w1, w3, b3, fc1w, fc1b, fc2w, fc2b,
                                             M, cvec, W31, c31);
    csr2_k<<<NB, 256, 0, stream>>>(binsbuf, cnts, gcur, ovbuf,
                                   csrp_s, nd_s, csr, be, lcnt3, n);

    int FB  = (n + 255) / 256;    // field/fieldsoft blocks
    int FBJ = (n + 15) / 16;      // j-parallel proj blocks (16 nodes/block)
    int AB  = (n + 15) / 16;      // agg blocks (4 nodes/wave, 4 waves/block)
    proj_k<<<FBJ, 256, 0, stream>>>(x, buf0, buf1, out, w1, b1, w2, b2,
                                    W31, c31, M, cvec, n);

    __half* cur = buf0;
    __half* nxt = buf1;
    // hop 1: agg only (field0 applied in proj)
    hop_k<<<AB, 256, 0, stream>>>(cur, nxt, out, csrp_s, nd_s, be, csr, lcnt3,
                                  w2, b1, b2, M, n, 0);
    { __half* t = cur; cur = nxt; nxt = t; }
    // hops 2..7: field(z_k, M_k) + agg(z_k -> z_{k+1}) in one launch
    for (int k = 1; k <= 6; k++) {
        hop_k<<<FB + AB, 256, 0, stream>>>(cur, nxt, out, csrp_s, nd_s, be, csr,
                                           lcnt3, w2, b1, b2, M + k * 128, n, FB);
        __half* t = cur; cur = nxt; nxt = t;
    }
    // final: field(z7, M7) + softmax
    fieldsoft_k<<<FB, 256, 0, stream>>>(cur, out, w2, b1, b2, M + 7 * 128, n);
}

// Round 11
// 234.967 us; speedup vs baseline: 1.1460x; 1.0349x over previous
//
#include <hip/hip_runtime.h>
#include <hip/hip_fp16.h>

// ---------------------------------------------------------------------------
// LinearAggActor R30 (R29 + csr2||proj merged launch + j-parallel fieldsoft):
//  - math (verified R2-R16): z0 = t2@(w3@w1)+b3@w1 (16-dim); z_k = A^k z0;
//    logits = cvec + sum_k relu(relu(z_k+b1)@w2+b2) @ M_k ; softmax.
//  - R25..R29 plateau: all kernel-internal opts land 240-246us. Remaining
//    structure: 11 serialized dispatches; csr2 (391 blocks ~1.5 waves/SIMD)
//    and fieldsoft (196 blocks) are latency-starved with no TLP cover.
//  - R30a: csr2+proj MERGED (role-split by blockIdx). R24's attempt died of
//    VGPR contamination (proj-TPN = 256 VGPR); R29's j-parallel proj is ~40
//    VGPR = csr2's league -> no contamination. LDS via union (27.7KB -> 5
//    blk/CU). csr2's starved blocks hide under proj's 3125-block sea:
//    wall ~= max instead of sum.
//  - R30b: fieldsoft j-parallel (16 lanes/node, shfl stages, xor-reduce
//    logits, cross-lane softmax 1 expf/lane, 3125 blocks).
//  - kept: fp16 z rows + uint2 gathers (R25), tier-sorted csrp_s/nd_s
//    2-epoch chain (R24), hop (256,4) (R25 verified), j-parallel proj (R29),
//    original cnts layout.
//  - build (R10-15): binfill multisplit + setup on idle CUs; sentinel row n.
// ---------------------------------------------------------------------------

#define NB2MAX 400   // bins of 128 dsts: supports n <= 51200
#define NBLK   256   // binfill blocks
#define CAP2   32    // LDS staging per bin
#define CAPC   48    // per-(bin,block) cell capacity (mean 16, +8 sigma)
#define CAPB   6144  // per-bin dense CSR region (overflow tails only)
#define OVCAP  1024  // per-bin overflow region (statistically unused)
#define LCAP   6144  // csr2 per-bin LDS capacity (mean 4096, +32 sigma)
#define CAPN   64    // padded slots per node (mean 32, +5.7 sigma)

// blocks [0,NBLK): multisplit into private (bin,block) cells; packed
// (dloc<<16|src); LDS cursors; no global atomics on the hot path.
// blocks [NBLK, NBLK+9): setup role (R10-verified).
__global__ __launch_bounds__(1024) void binfill_k(
    const int* __restrict__ src, const int* __restrict__ dst, int E, int n,
    int* __restrict__ gcur, int* __restrict__ ovbuf,
    int* __restrict__ bins, int* __restrict__ cnts,
    const float* __restrict__ w1, const float* __restrict__ w3,
    const float* __restrict__ b3, const float* __restrict__ fc1w,
    const float* __restrict__ fc1b, const float* __restrict__ fc2w,
    const float* __restrict__ fc2b,
    float* __restrict__ M, float* __restrict__ cvec,
    float* __restrict__ W31, float* __restrict__ c31) {
    __shared__ int lbuf[NB2MAX * CAP2];
    __shared__ int lcnt[NB2MAX];
    __shared__ int lflush[NB2MAX];
    int tid = threadIdx.x;
    int NB = (n + 127) >> 7;

    if ((int)blockIdx.x >= NBLK) {
        // ---------------- setup role ----------------
        float* fl = (float*)lbuf;   // LDS reuse
        int s = (int)blockIdx.x - NBLK;
        if (s == 0) {
            if (tid < 256) {
                int i = tid >> 4, j = tid & 15;
                float a = 0.f;
                for (int g = 0; g < 64; g++) a += w3[i * 64 + g] * w1[g * 16 + j];
                W31[tid] = a;
            } else if (tid < 272) {
                int j = tid - 256;
                float a = 0.f;
                for (int g = 0; g < 64; g++) a += b3[g] * w1[g * 16 + j];
                c31[j] = a;
            } else if (tid >= 320 && tid < 384) {
                int h = tid - 320;
                float a = 0.f;
                for (int r = 0; r < 512; r++) a += b3[r & 63] * fc1w[r * 64 + h];
                fl[h] = a;   // u[h]
            }
            __syncthreads();
            if (tid < 8) {
                float a = fc2b[tid];
                for (int h = 0; h < 64; h++) a += (fc1b[h] + fl[h]) * fc2w[h * 8 + tid];
                cvec[tid] = a;
            }
        } else {
            int k = s - 1;
            {   // Q_k: one elem per thread
                int i = tid >> 6, h = tid & 63;
                float a = 0.f;
                const float* f1 = fc1w + (size_t)(k * 64) * 64 + h;
                for (int g = 0; g < 64; g++) a += w3[i * 64 + g] * f1[g * 64];
                fl[i * 64 + h] = a;
            }
            __syncthreads();
            if (tid < 128) {
                int i = tid >> 3, j = tid & 7;
                float a = 0.f;
                for (int h = 0; h < 64; h++) a += fl[i * 64 + h] * fc2w[h * 8 + j];
                M[k * 128 + i * 8 + j] = a;
            }
        }
        return;
    }

    // ---------------- binfill role ----------------
    for (int b = tid; b < NB; b += 1024) { lcnt[b] = 0; lflush[b] = 0; }
    __syncthreads();
    int blk = blockIdx.x;
    int chunk = (E + NBLK - 1) / NBLK;
    int beg = blk * chunk;
    int end = beg + chunk; if (end > E) end = E;
    for (int t0 = beg; t0 < end; t0 += 1024) {
        int e = t0 + tid;
        if (e < end) {
            int d = dst[e], s = src[e];
            if ((unsigned)d < (unsigned)n && (unsigned)s < (unsigned)n) {
                int b = d >> 7;
                int pk = ((d & 127) << 16) | s;
                int pos = atomicAdd(&lcnt[b], 1);
                if (pos < CAP2) lbuf[b * CAP2 + pos] = pk;
                else {  // statistically never
                    int p = atomicAdd(&gcur[b], 1);
                    if (p < OVCAP) ovbuf[b * OVCAP + p] = pk;
                }
            }
        }
        __syncthreads();
        for (int b = tid; b < NB; b += 1024) {
            int cnt = lcnt[b]; if (cnt > CAP2) cnt = CAP2;
            int fl2 = lflush[b];
            size_t cell = ((size_t)b * NBLK + blk) * CAPC;
            int base = 0;
            while (cnt - base >= 16) {
                if (fl2 + 16 <= CAPC) {
                    int* dp = bins + cell + fl2;
                    #pragma unroll
                    for (int q = 0; q < 16; q++) dp[q] = lbuf[b * CAP2 + base + q];
                    fl2 += 16;
                } else {  // cell overflow (statistically never)
                    int p = atomicAdd(&gcur[b], 16);
                    for (int q = 0; q < 16; q++)
                        if (p + q < OVCAP) ovbuf[b * OVCAP + p + q] = lbuf[b * CAP2 + base + q];
                }
                base += 16;
            }
            int rem = cnt - base;
            if (base > 0)
                for (int q = 0; q < rem; q++) lbuf[b * CAP2 + q] = lbuf[b * CAP2 + base + q];
            lcnt[b] = rem; lflush[b] = fl2;
        }
        __syncthreads();
    }
    for (int b = tid; b < NB; b += 1024) {
        int cnt = lcnt[b]; if (cnt > CAP2) cnt = CAP2;
        int fl2 = lflush[b];
        size_t cell = ((size_t)b * NBLK + blk) * CAPC;
        if (fl2 + cnt <= CAPC) {
            for (int q = 0; q < cnt; q++) bins[cell + fl2 + q] = lbuf[b * CAP2 + q];
            fl2 += cnt;
        } else {
            int p = atomicAdd(&gcur[b], cnt);
            for (int q = 0; q < cnt; q++)
                if (p + q < OVCAP) ovbuf[b * OVCAP + p + q] = lbuf[b * CAP2 + q];
        }
        cnts[(size_t)blk * NB + b] = fl2;
    }
}

// Merged launch (R30a). Blocks [0,NB): csr2 role (low VGPR, latency-bound,
// hides under proj's block sea). Blocks [NB, NB+FBJ): j-parallel proj role
// (R29-verified, ~40 VGPR). LDS via union: 27.7KB -> 5 blocks/CU.
struct SmemC {   // csr2 role
    int hist[128], pref[128], cur[128], slot[128];
    int scnt[NBLK];
    int lbuf[LCAP];
    int sov;
    int ccnt[3], cbase[3];
};
struct SmemP {   // proj role
    float sx[16 * 68];
    float sw1[1024], sw2[256], sW[256], sM[128];
    float sb1[16], sb2[16], sc[16], scv[8];
};
union SmemU { SmemC c; SmemP p; };

__global__ __launch_bounds__(256) void csr2proj_k(
    const int* __restrict__ bins, const int* __restrict__ cnts,
    const int* __restrict__ gcur, const int* __restrict__ ovbuf,
    unsigned short* __restrict__ csrp_s, int2* __restrict__ nd_s,
    int* __restrict__ csr, int2* __restrict__ be, int* __restrict__ lcnt3,
    const float* __restrict__ x, __half* __restrict__ z0, __half* __restrict__ z1,
    float* __restrict__ logits,
    const float* __restrict__ w1, const float* __restrict__ b1,
    const float* __restrict__ w2, const float* __restrict__ b2,
    const float* __restrict__ W31, const float* __restrict__ c31,
    const float* __restrict__ M0, const float* __restrict__ cvec,
    int n, int NBARG) {
    __shared__ SmemU smem;
    int tid = threadIdx.x;
    if ((int)blockIdx.x < NBARG) {
        // ======================= csr2 role =======================
        SmemC& sc_ = smem.c;
        int NB = NBARG;
        int b = blockIdx.x;
        if (tid < 128) { sc_.hist[tid] = 0; sc_.cur[tid] = 0; }
        if (tid < 3) sc_.ccnt[tid] = 0;
        sc_.scnt[tid] = cnts[(size_t)tid * NB + b];
        if (tid == 0) {
            int g = gcur[b];
            sc_.sov = g < 0 ? 0 : (g > OVCAP ? OVCAP : g);
        }
        __syncthreads();
        {   // pass 1: histogram of dst-local
            int c = sc_.scnt[tid];
            size_t cell = ((size_t)b * NBLK + tid) * CAPC;
            for (int i = 0; i < c; i++) atomicAdd(&sc_.hist[bins[cell + i] >> 16], 1);
        }
        if (tid == 0)
            for (int i = 0; i < sc_.sov; i++)
                atomicAdd(&sc_.hist[ovbuf[b * OVCAP + i] >> 16], 1);
        __syncthreads();
        if (tid == 0) {
            int r = 0;
            for (int i = 0; i < 128; i++) { sc_.pref[i] = r; r += sc_.hist[i]; }
        }
        __syncthreads();
        {   // pass 2: place into LDS (bin-locally dense, sorted by dst)
            int c = sc_.scnt[tid];
            size_t cell = ((size_t)b * NBLK + tid) * CAPC;
            for (int i = 0; i < c; i++) {
                int pk = bins[cell + i];
                int dl = pk >> 16;
                int pos = sc_.pref[dl] + atomicAdd(&sc_.cur[dl], 1);
                if (pos < LCAP) sc_.lbuf[pos] = pk & 0xffff;
            }
        }
        if (tid == 0) {
            for (int i = 0; i < sc_.sov; i++) {
                int pk = ovbuf[b * OVCAP + i];
                int dl = pk >> 16;
                int pos = sc_.pref[dl] + atomicAdd(&sc_.cur[dl], 1);
                if (pos < LCAP) sc_.lbuf[pos] = pk & 0xffff;
            }
        }
        __syncthreads();
        // tier classification -> global sorted slot per node
        int myc = -1, lpos = 0;
        if (tid < 128) {
            int d = (b << 7) + tid;
            if (d < n) {
                int cnt = sc_.hist[tid];
                myc = cnt <= 32 ? 0 : (cnt <= 48 ? 1 : 2);
                lpos = atomicAdd(&sc_.ccnt[myc], 1);
            }
        }
        __syncthreads();
        if (tid < 3) sc_.cbase[tid] = atomicAdd(&lcnt3[tid], sc_.ccnt[tid]);
        __syncthreads();
        if (myc >= 0) {
            int d = (b << 7) + tid;
            int cnt = sc_.hist[tid];
            int s = myc * n + sc_.cbase[myc] + lpos;   // region base myc*n
            sc_.slot[tid] = s;
            nd_s[s] = make_int2(d, cnt);
            if (cnt > CAPN) {   // rare tail -> dense region + be (premult x4)
                int s0 = b * CAPB + sc_.pref[tid];
                be[d] = make_int2(s0 + CAPN, s0 + cnt);
                for (int j = CAPN; j < cnt; j++)
                    csr[s0 + j] = sc_.lbuf[sc_.pref[tid] + j] << 2;
            }
        }
        __syncthreads();
        // permuted padded ushort CSR into sorted row; sentinel = n (zero row)
        for (int q = tid; q < 128 * CAPN; q += 256) {
            int dl = q >> 6, j = q & 63;
            int d = (b << 7) + dl;
            if (d >= n) break;
            int cnt = sc_.hist[dl];
            int v = (j < cnt) ? sc_.lbuf[sc_.pref[dl] + j] : n;
            int pos = ((j & 3) << 4) | (j >> 2);
            csrp_s[(size_t)sc_.slot[dl] * CAPN + pos] = (unsigned short)v;
        }
        return;
    }
    // ======================= proj role (j-parallel, R29) =======================
    SmemP& sp = smem.p;
    for (int i = tid; i < 1024; i += 256) sp.sw1[i] = w1[i];
    sp.sw2[tid] = w2[tid];
    sp.sW[tid] = W31[tid];
    if (tid < 128) sp.sM[tid] = M0[tid];
    if (tid < 16) { sp.sb1[tid] = b1[tid]; sp.sb2[tid] = b2[tid]; sp.sc[tid] = c31[tid]; }
    if (tid < 8) sp.scv[tid] = cvec[tid];
    if ((int)blockIdx.x == NBARG && tid < 16) {   // zero sentinel row n
        ((unsigned short*)z0)[(size_t)n * 16 + tid] = 0;
        ((unsigned short*)z1)[(size_t)n * 16 + tid] = 0;
    }
    int node0 = ((int)blockIdx.x - NBARG) * 16;
    {   // stage x: 16 rows x 64 floats, coalesced float4
        int r = tid >> 4, c4 = tid & 15;
        if (node0 + r < n) {
            float4 v = ((const float4*)(x + (size_t)(node0 + r) * 64))[c4];
            float* dstp = sp.sx + r * 68 + c4 * 4;
            dstp[0] = v.x; dstp[1] = v.y; dstp[2] = v.z; dstp[3] = v.w;
        }
    }
    __syncthreads();
    int nl = tid >> 4, jj = tid & 15;
    int node = node0 + nl;
    if (node >= n) return;
    float t1 = 0.f;
    const float* xr = sp.sx + nl * 68;
    #pragma unroll
    for (int g = 0; g < 64; g++) t1 += xr[g] * sp.sw1[g * 16 + jj];
    t1 = fmaxf(t1 + sp.sb1[jj], 0.f);
    float t2 = sp.sb2[jj];
    #pragma unroll
    for (int i = 0; i < 16; i++) t2 += __shfl(t1, i, 16) * sp.sw2[i * 16 + jj];
    t2 = fmaxf(t2, 0.f);
    float zv = sp.sc[jj];
    #pragma unroll
    for (int i = 0; i < 16; i++) zv += __shfl(t2, i, 16) * sp.sW[i * 16 + jj];
    z0[(size_t)node * 16 + jj] = __float2half(zv);
    float hv = fmaxf(zv + sp.sb1[jj], 0.f);
    float f2 = sp.sb2[jj];
    #pragma unroll
    for (int i = 0; i < 16; i++) f2 += __shfl(hv, i, 16) * sp.sw2[i * 16 + jj];
    f2 = fmaxf(f2, 0.f);
    float p0 = f2 * sp.sM[jj * 8 + 0], p1 = f2 * sp.sM[jj * 8 + 1];
    float p2 = f2 * sp.sM[jj * 8 + 2], p3 = f2 * sp.sM[jj * 8 + 3];
    float p4 = f2 * sp.sM[jj * 8 + 4], p5 = f2 * sp.sM[jj * 8 + 5];
    float p6 = f2 * sp.sM[jj * 8 + 6], p7 = f2 * sp.sM[jj * 8 + 7];
    #pragma unroll
    for (int off = 1; off < 16; off <<= 1) {
        p0 += __shfl_xor(p0, off, 16); p1 += __shfl_xor(p1, off, 16);
        p2 += __shfl_xor(p2, off, 16); p3 += __shfl_xor(p3, off, 16);
        p4 += __shfl_xor(p4, off, 16); p5 += __shfl_xor(p5, off, 16);
        p6 += __shfl_xor(p6, off, 16); p7 += __shfl_xor(p7, off, 16);
    }
    if (jj < 8) {   // compile-time select chain (no runtime reg indexing)
        float myp = jj == 0 ? p0 : jj == 1 ? p1 : jj == 2 ? p2 : jj == 3 ? p3
                  : jj == 4 ? p4 : jj == 5 ? p5 : jj == 6 ? p6 : p7;
        logits[(size_t)node * 8 + jj] = sp.scv[jj] + myp;
    }
}

// unpack one uint2 (4 halfs = one channel quad) and accumulate
__device__ __forceinline__ void acc_row(uint2 u, float& ax, float& ay,
                                        float& az, float& aw) {
    __half2 p = *reinterpret_cast<const __half2*>(&u.x);
    __half2 q = *reinterpret_cast<const __half2*>(&u.y);
    float2 f = __half22float2(p), g = __half22float2(q);
    ax += f.x; ay += f.y; az += g.x; aw += g.y;
}

// One launch per hop. Blocks [0,FB): field(z_k) thread-per-node;
// blocks [FB,..): agg, 4 nodes/wave (16 lanes = 4 slot-groups x 4 chan-quads).
// z rows = 16 halfs = 32B; lane reads uint2; tier-sorted rows (2-epoch chain):
// tier0 8 gathers, tier1 12, tier2 16 + dense tail. (256,4) = R25 verified.
__global__ __launch_bounds__(256, 4) void hop_k(
    const __half* __restrict__ zin, __half* __restrict__ zout,
    float* __restrict__ logits,
    const unsigned short* __restrict__ csrp_s, const int2* __restrict__ nd_s,
    const int2* __restrict__ be, const int* __restrict__ csr,
    const int* __restrict__ lcnt3,
    const float* __restrict__ w2, const float* __restrict__ b1,
    const float* __restrict__ b2, const float* __restrict__ M, int n, int FB) {
    __shared__ float sw2[256], sM[128], sb1[16], sb2[16];
    int tid = threadIdx.x;
    if ((int)blockIdx.x < FB) {
        // ---- field role ----
        sw2[tid] = w2[tid];
        if (tid < 128) sM[tid] = M[tid];
        if (tid < 16) { sb1[tid] = b1[tid]; sb2[tid] = b2[tid]; }
        __syncthreads();
        int nid = blockIdx.x * 256 + tid;
        if (nid >= n) return;
        float h[16];
        const __half2* zp = (const __half2*)(zin + (size_t)nid * 16);
        #pragma unroll
        for (int q = 0; q < 8; q++) {
            float2 f = __half22float2(zp[q]);
            h[2 * q] = f.x; h[2 * q + 1] = f.y;
        }
        #pragma unroll
        for (int i = 0; i < 16; i++) h[i] = fmaxf(h[i] + sb1[i], 0.f);
        float t2[16];
        #pragma unroll
        for (int j = 0; j < 16; j++) {
            float a = sb2[j];
            #pragma unroll
            for (int i = 0; i < 16; i++) a += h[i] * sw2[i * 16 + j];
            t2[j] = fmaxf(a, 0.f);
        }
        float* lp = logits + (size_t)nid * 8;
        #pragma unroll
        for (int j = 0; j < 8; j++) {
            float l = 0.f;
            #pragma unroll
            for (int i = 0; i < 16; i++) l += t2[i] * sM[i * 8 + j];
            lp[j] += l;
        }
        return;
    }
    // ---- agg role: 4 nodes per wave, tier-sorted direct rows ----
    int wave = tid >> 6;
    int lane = tid & 63;
    int quarter = lane >> 4;              // which node of the 4
    int l16 = lane & 15;
    int t4 = l16 >> 2, ch = l16 & 3;      // slot-group 0..3, chan-quad 0..3
    int idx = (((int)blockIdx.x - FB) * 4 + wave) * 4 + quarter;
    if (idx >= n) return;
    int ns = lcnt3[0], nm = lcnt3[1];     // uniform scalar loads
    int tier; size_t row;
    if (idx < ns)           { tier = 0; row = (size_t)idx; }
    else if (idx < ns + nm) { tier = 1; row = (size_t)n + (idx - ns); }
    else                    { tier = 2; row = 2 * (size_t)n + (idx - ns - nm); }
    int2 nd = nd_s[row];                  // {node, deg} — same epoch as ip
    int node = nd.x, degi = nd.y;
    const uint4* ip = (const uint4*)(csrp_s + (row << 6));
    uint4 pa = ip[t4 * 2];                // sorted slots j = t4, t4+4, ..., t4+28
    int r0 = pa.x & 0xffff, r1 = pa.x >> 16;
    int r2 = pa.y & 0xffff, r3 = pa.y >> 16;
    int r4 = pa.z & 0xffff, r5 = pa.z >> 16;
    int r6 = pa.w & 0xffff, r7 = pa.w >> 16;
    const uint2* z2 = (const uint2*)zin;  // row stride = 4 uint2 (32B)
    uint2 u0 = z2[((size_t)r0 << 2) + ch];   // sentinel n -> zero row
    uint2 u1 = z2[((size_t)r1 << 2) + ch];
    uint2 u2 = z2[((size_t)r2 << 2) + ch];
    uint2 u3 = z2[((size_t)r3 << 2) + ch];
    uint2 u4 = z2[((size_t)r4 << 2) + ch];
    uint2 u5 = z2[((size_t)r5 << 2) + ch];
    uint2 u6 = z2[((size_t)r6 << 2) + ch];
    uint2 u7 = z2[((size_t)r7 << 2) + ch];
    float ax = 0.f, ay = 0.f, az = 0.f, aw = 0.f;
    acc_row(u0, ax, ay, az, aw); acc_row(u1, ax, ay, az, aw);
    acc_row(u2, ax, ay, az, aw); acc_row(u3, ax, ay, az, aw);
    acc_row(u4, ax, ay, az, aw); acc_row(u5, ax, ay, az, aw);
    acc_row(u6, ax, ay, az, aw); acc_row(u7, ax, ay, az, aw);
    if (tier >= 1) {
        uint4 pb = ip[t4 * 2 + 1];        // sorted slots j = t4+32..t4+60
        int r8 = pb.x & 0xffff, r9 = pb.x >> 16;
        int rA = pb.y & 0xffff, rB = pb.y >> 16;
        uint2 u8 = z2[((size_t)r8 << 2) + ch];
        uint2 u9 = z2[((size_t)r9 << 2) + ch];
        uint2 uA = z2[((size_t)rA << 2) + ch];
        uint2 uB = z2[((size_t)rB << 2) + ch];
        acc_row(u8, ax, ay, az, aw); acc_row(u9, ax, ay, az, aw);
        acc_row(uA, ax, ay, az, aw); acc_row(uB, ax, ay, az, aw);
        if (tier == 2) {
            int rC = pb.z & 0xffff, rD = pb.z >> 16;
            int rE = pb.w & 0xffff, rF = pb.w >> 16;
            uint2 uC = z2[((size_t)rC << 2) + ch];
            uint2 uD = z2[((size_t)rD << 2) + ch];
            uint2 uE = z2[((size_t)rE << 2) + ch];
            uint2 uF = z2[((size_t)rF << 2) + ch];
            acc_row(uC, ax, ay, az, aw); acc_row(uD, ax, ay, az, aw);
            acc_row(uE, ax, ay, az, aw); acc_row(uF, ax, ay, az, aw);
            if (degi > CAPN) {            // rare tail via dense csr (4 slots)
                int2 r = be[node];
                for (int q = r.x + t4; q < r.y; q += 4) {
                    uint2 u = z2[(size_t)csr[q] + ch];   // csr premult x4
                    acc_row(u, ax, ay, az, aw);
                }
            }
        }
    }
    // reduce over 4 slot-groups within this 16-lane quarter
    #pragma unroll
    for (int off = 8; off >= 4; off >>= 1) {
        ax += __shfl_down(ax, off, 16);
        ay += __shfl_down(ay, off, 16);
        az += __shfl_down(az, off, 16);
        aw += __shfl_down(aw, off, 16);
    }
    if (l16 < 4) {
        float inv = 1.f / (float)(degi > 0 ? degi : 1);
        __half2 h01 = __floats2half2_rn(ax * inv, ay * inv);
        __half2 h23 = __floats2half2_rn(az * inv, aw * inv);
        uint2 w;
        w.x = *reinterpret_cast<unsigned int*>(&h01);
        w.y = *reinterpret_cast<unsigned int*>(&h23);
        ((uint2*)(zout + (size_t)node * 16))[l16] = w;
    }
}

// final (R30b): logits += field(z7, M7); softmax. J-PARALLEL, 16 lanes/node:
// lane jj owns dim jj; stages via __shfl; logits xor-reduce (all lanes get
// full sums); softmax cross-lane width-8 (1 expf/lane); coalesced stores.
__global__ __launch_bounds__(256, 4) void fieldsoft_k(
    const __half* __restrict__ z, float* __restrict__ logits,
    const float* __restrict__ w2, const float* __restrict__ b1,
    const float* __restrict__ b2, const float* __restrict__ M, int n) {
    __shared__ float sw2[256], sM[128], sb1[16], sb2[16];
    int tid = threadIdx.x;
    sw2[tid] = w2[tid];
    if (tid < 128) sM[tid] = M[tid];
    if (tid < 16) { sb1[tid] = b1[tid]; sb2[tid] = b2[tid]; }
    __syncthreads();
    int nl = tid >> 4, jj = tid & 15;
    int node = blockIdx.x * 16 + nl;
    if (node >= n) return;
    // lane jj loads z[node][jj]: 32B/node, contiguous 128B per 4-node wave
    float zv = __half2float(z[(size_t)node * 16 + jj]);
    float hv = fmaxf(zv + sb1[jj], 0.f);
    float t2 = sb2[jj];
    #pragma unroll
    for (int i = 0; i < 16; i++) t2 += __shfl(hv, i, 16) * sw2[i * 16 + jj];
    t2 = fmaxf(t2, 0.f);
    float p0 = t2 * sM[jj * 8 + 0], p1 = t2 * sM[jj * 8 + 1];
    float p2 = t2 * sM[jj * 8 + 2], p3 = t2 * sM[jj * 8 + 3];
    float p4 = t2 * sM[jj * 8 + 4], p5 = t2 * sM[jj * 8 + 5];
    float p6 = t2 * sM[jj * 8 + 6], p7 = t2 * sM[jj * 8 + 7];
    #pragma unroll
    for (int off = 1; off < 16; off <<= 1) {
        p0 += __shfl_xor(p0, off, 16); p1 += __shfl_xor(p1, off, 16);
        p2 += __shfl_xor(p2, off, 16); p3 += __shfl_xor(p3, off, 16);
        p4 += __shfl_xor(p4, off, 16); p5 += __shfl_xor(p5, off, 16);
        p6 += __shfl_xor(p6, off, 16); p7 += __shfl_xor(p7, off, 16);
    }
    // all 16 lanes now hold the full p0..p7. Lane jj works on logit q=jj&7
    // (lanes 8-15 mirror 0-7 so width-8 shuffles are well-defined).
    int q = jj & 7;
    float myp = q == 0 ? p0 : q == 1 ? p1 : q == 2 ? p2 : q == 3 ? p3
              : q == 4 ? p4 : q == 5 ? p5 : q == 6 ? p6 : p7;
    float lg = myp + logits[(size_t)node * 8 + q];
    float m = lg;
    m = fmaxf(m, __shfl_xor(m, 1, 8));
    m = fmaxf(m, __shfl_xor(m, 2, 8));
    m = fmaxf(m, __shfl_xor(m, 4, 8));
    float e = expf(lg - m);
    float s = e;
    s += __shfl_xor(s, 1, 8);
    s += __shfl_xor(s, 2, 8);
    s += __shfl_xor(s, 4, 8);
    if (jj < 8) logits[(size_t)node * 8 + jj] = e / s;
}

extern "C" void kernel_launch(void* const* d_in, const int* in_sizes, int n_in,
                              void* d_out, int out_size, void* d_ws, size_t ws_size,
                              hipStream_t stream) {
    const float* x    = (const float*)d_in[0];
    const int*   ei   = (const int*)d_in[1];
    const float* w1   = (const float*)d_in[2];
    const float* b1   = (const float*)d_in[3];
    const float* w2   = (const float*)d_in[4];
    const float* b2   = (const float*)d_in[5];
    const float* w3   = (const float*)d_in[6];
    const float* b3   = (const float*)d_in[7];
    const float* fc1w = (const float*)d_in[8];
    const float* fc1b = (const float*)d_in[9];
    const float* fc2w = (const float*)d_in[10];
    const float* fc2b = (const float*)d_in[11];
    float* out = (float*)d_out;

    int n = in_sizes[0] / 64;
    int E = in_sizes[1] / 2;
    int NB = (n + 127) >> 7;   // 391 for n=50000; NB <= NB2MAX
    const int* src = ei;
    const int* dst = ei + E;

    char* ws = (char*)d_ws;
    auto carve = [&](size_t bytes) {
        char* p = ws;
        ws += (bytes + 255) & ~((size_t)255);
        return p;
    };
    int*   gcur    = (int*)carve((size_t)NB * 4);
    int*   lcnt3   = (int*)carve(16);                 // contiguous after gcur pad
    int*   ovbuf   = (int*)carve((size_t)NB * OVCAP * 4);
    int*   binsbuf = (int*)carve((size_t)NB * NBLK * CAPC * 4);
    int*   cnts    = (int*)carve((size_t)NBLK * NB * 4);
    unsigned short* csrp_s = (unsigned short*)carve((size_t)3 * n * CAPN * 2); // tier-sorted
    int2*  nd_s    = (int2*)carve((size_t)3 * n * 8);                          // {node,deg}
    int*   csr     = (int*)carve((size_t)NB * CAPB * 4);
    int2*  be      = (int2*)carve((size_t)n * 8);
    __half* buf0   = (__half*)carve((size_t)(n + 1) * 16 * 2);  // +1 zero row
    __half* buf1   = (__half*)carve((size_t)(n + 1) * 16 * 2);
    float* M       = (float*)carve(1024 * 4);
    float* cvec    = (float*)carve(8 * 4);
    float* W31     = (float*)carve(256 * 4);
    float* c31     = (float*)carve(16 * 4);

    // one memset covers gcur (padded to 256) + lcnt3 (next carve slot)
    size_t gpad = ((size_t)NB * 4 + 255) & ~((size_t)255);
    hipMemsetAsync(gcur, 0, gpad + 16, stream);
    binfill_k<<<NBLK + 9, 1024, 0, stream>>>(src, dst, E, n, gcur, ovbuf, binsbuf, cnts,
                                             w1, w3, b3, fc1w, fc1b, fc2w, fc2b,
                                             M, cvec, W31, c31);

    int FB  = (n + 255) / 256;    // hop field blocks
    int FBJ = (n + 15) / 16;      // j-parallel proj/fieldsoft blocks
    int AB  = (n + 15) / 16;      // agg blocks (4 nodes/wave, 4 waves/block)
    // merged csr2 || proj (R30a): csr2's 391 starved blocks hide under
    // proj's 3125-block sea; both low-VGPR now (R24 contamination gone).
    csr2proj_k<<<NB + FBJ, 256, 0, stream>>>(binsbuf, cnts, gcur, ovbuf,
                                             csrp_s, nd_s, csr, be, lcnt3,
                                             x, buf0, buf1, out, w1, b1, w2, b2,
                                             W31, c31, M, cvec, n, NB);

    __half* cur = buf0;
    __half* nxt = buf1;
    // hop 1: agg only (field0 applied in proj)
    hop_k<<<AB, 256, 0, stream>>>(cur, nxt, out, csrp_s, nd_s, be, csr, lcnt3,
                                  w2, b1, b2, M, n, 0);
    { __half* t = cur; cur = nxt; nxt = t; }
    // hops 2..7: field(z_k, M_k) + agg(z_k -> z_{k+1}) in one launch
    for (int k = 1; k <= 6; k++) {
        hop_k<<<FB + AB, 256, 0, stream>>>(cur, nxt, out, csrp_s, nd_s, be, csr,
                                           lcnt3, w2, b1, b2, M + k * 128, n, FB);
        __half* t = cur; cur = nxt; nxt = t;
    }
    // final: field(z7, M7) + softmax (j-parallel, R30b)
    fieldsoft_k<<<FBJ, 256, 0, stream>>>(cur, out, w2, b1, b2, M + 7 * 128, n);
}